// Round 15
// baseline (264.669 us; speedup 1.0000x reference)
//
#include <hip/hip_runtime.h>

#define ROWS_TOTAL 131072
#define XST 224             // g_xb row stride in bf16 elements (448 B, zero-padded)

typedef float f32x4 __attribute__((ext_vector_type(4)));
typedef short s16x8 __attribute__((ext_vector_type(8)));

// W fragment-linear, per 16-col n-frag:
//   byte = (n*7 + kk)*1024 + col16*64 + ks*16 + e*2   (zero-padded k>=196)
__device__ unsigned short g_Wb4[49 * 7 * 16 * 32];          // 351 KB
// x patchified, bf16, row stride 224 ushorts (zero-padded k = 196..223)
__device__ unsigned short g_xb[(size_t)ROWS_TOTAL * XST];   // 58.7 MB

__device__ __forceinline__ unsigned short f2bf(float f) {
    unsigned int u = __builtin_bit_cast(unsigned int, f);
    u += 0x7fffu + ((u >> 16) & 1u);        // round-to-nearest-even
    return (unsigned short)(u >> 16);
}

__global__ void prep_w(const float* __restrict__ W) {
    int t = blockIdx.x * 256 + threadIdx.x;   // 784 cols * 56 k-quads
    if (t >= 784 * 56) return;
    int col = t / 56;
    int k0  = (t - col * 56) * 4;
    uint2 pk;
    if (k0 < 196) {
        f32x4 d = *(const f32x4*)(W + col * 196 + k0);
        pk.x = (unsigned int)f2bf(d[0]) | ((unsigned int)f2bf(d[1]) << 16);
        pk.y = (unsigned int)f2bf(d[2]) | ((unsigned int)f2bf(d[3]) << 16);
    } else {
        pk.x = 0u; pk.y = 0u;
    }
    int ng = col >> 4, col16 = col & 15;
    int kk = k0 >> 5, rem = k0 & 31, ks = rem >> 3, e0 = rem & 7;
    size_t di = (size_t)((ng * 7 + kk) * 16 + col16) * 32 + ks * 8 + e0;
    *(uint2*)(g_Wb4 + di) = pk;
}

// patchify: x[32768,28,28] fp32 -> g_xb[131072][224] bf16 (zero-padded)
__global__ void prep_x(const float* __restrict__ x) {
    const int NV = ROWS_TOTAL / 4 * 784 / 4;            // 6,422,528 float4s
    const f32x4* xv = (const f32x4*)x;
    for (int v = blockIdx.x * 256 + threadIdx.x; v < NV; v += gridDim.x * 256) {
        f32x4 d = xv[v];
        int F   = v * 4;
        int img = F / 784;
        int rem = F - img * 784;
        int h   = rem / 28;
        int w0  = rem - h * 28;          // in {0,4,...,24}
        int ph  = h / 14;
        int r   = h - ph * 14;
        int rowb = img * 4 + ph * 2;
        #pragma unroll
        for (int p = 0; p < 2; ++p) {
            int w  = w0 + 2 * p;         // even => bf16 pair stays inside one patch
            int pw = (w >= 14) ? 1 : 0;
            int c  = w - pw * 14;
            int row = rowb + pw;
            unsigned int pack = (unsigned int)f2bf(d[2 * p]) |
                                ((unsigned int)f2bf(d[2 * p + 1]) << 16);
            *(unsigned int*)((char*)g_xb + (size_t)row * (XST * 2) + (r * 14 + c) * 2) = pack;
        }
    }
    // zero pad k = 196..223 for every row
    for (int t = blockIdx.x * 256 + threadIdx.x; t < ROWS_TOTAL * 7; t += gridDim.x * 256) {
        int row = t / 7;
        int j   = t - row * 7;
        *(uint2*)((char*)g_xb + (size_t)row * (XST * 2) + 392 + j * 8) = (uint2){0u, 0u};
    }
}

// Pure streaming GEMM: NO LDS, NO barriers, NO DMA. Wave owns 32 output cols
// (2 n-frags; W held in 56 VGPR) and loops over 16-row tiles (stride 120):
//   { 7 xf dwordx4 loads -> 14 MFMA -> 2 dwordx4 stores }.
// ~130 VGPR -> 3 waves/SIMD; 750 co-resident blocks keep x L2/L3-hot and the
// store stream continuous (fillBuffer saturates writes at ~3.5 waves/CU).
// Col-group 24 is 16 wide: its 2nd frag duplicates the 1st (benign dup store).
__global__ __launch_bounds__(256, 3)
void patch_linear_mfma(const float* __restrict__ blin,
                       float* __restrict__ out) {
    const int tid  = threadIdx.x;
    const int l    = tid & 63;
    const int wv   = tid >> 6;          // 0..3
    const int lrow = l & 15;
    const int lk   = l >> 4;

    const int cg = blockIdx.x;          // 0..24 (32-col group)
    const int n0 = cg * 2;
    const int n1 = (n0 + 1 < 49) ? n0 + 1 : n0;

    // ---- W fragments -> registers, once (coalesced 16x64B per load) ----
    s16x8 wf[2][7];
    {
        const char* w0 = (const char*)g_Wb4 + (size_t)(n0 * 7) * 1024 + lrow * 64 + lk * 16;
        const char* w1 = (const char*)g_Wb4 + (size_t)(n1 * 7) * 1024 + lrow * 64 + lk * 16;
        #pragma unroll
        for (int kk = 0; kk < 7; ++kk) {
            wf[0][kk] = *(const s16x8*)(w0 + kk * 1024);
            wf[1][kk] = *(const s16x8*)(w1 + kk * 1024);
        }
    }
    // bias (loop-invariant)
    const f32x4 b0 = *(const f32x4*)(blin + n0 * 16 + lk * 4);
    const f32x4 b1 = *(const f32x4*)(blin + n1 * 16 + lk * 4);

    // ---- steady-state row-tile loop ----
    for (int rt = blockIdx.y * 4 + wv; rt < ROWS_TOTAL / 16; rt += 120) {
        const char* xb = (const char*)g_xb + ((size_t)rt * 16 + lrow) * 448 + lk * 16;
        s16x8 xf[7];
        #pragma unroll
        for (int kk = 0; kk < 7; ++kk)
            xf[kk] = *(const s16x8*)(xb + kk * 64);

        f32x4 acc0 = b0, acc1 = b1;
        #pragma unroll
        for (int kk = 0; kk < 7; ++kk) {
            acc0 = __builtin_amdgcn_mfma_f32_16x16x32_bf16(wf[0][kk], xf[kk], acc0, 0, 0, 0);
            acc1 = __builtin_amdgcn_mfma_f32_16x16x32_bf16(wf[1][kk], xf[kk], acc1, 0, 0, 0);
        }

        float* orow = out + ((size_t)rt * 16 + lrow) * 784 + lk * 4;
        *(f32x4*)(orow + n0 * 16) = acc0;
        *(f32x4*)(orow + n1 * 16) = acc1;
    }
}

extern "C" void kernel_launch(void* const* d_in, const int* in_sizes, int n_in,
                              void* d_out, int out_size, void* d_ws, size_t ws_size,
                              hipStream_t stream) {
    const float* x    = (const float*)d_in[0];   // [32768,1,28,28]
    const float* Wlin = (const float*)d_in[1];   // [784,196]
    const float* blin = (const float*)d_in[2];   // [784]
    float* out = (float*)d_out;                  // [32768,4,784]

    prep_w<<<(784 * 56 + 255) / 256, 256, 0, stream>>>(Wlin);
    prep_x<<<4096, 256, 0, stream>>>(x);

    dim3 grid(25, 30);                           // 750 blocks, all co-resident
    dim3 block(256);
    patch_linear_mfma<<<grid, block, 0, stream>>>(blin, out);
}

// Round 16
// 223.168 us; speedup vs baseline: 1.1860x; 1.1860x over previous
//
#include <hip/hip_runtime.h>

#define ROWS_TOTAL 131072
#define XST 224             // g_xb row stride in bf16 elements (448 B, zero-padded)

typedef float f32x4 __attribute__((ext_vector_type(4)));
typedef short s16x8 __attribute__((ext_vector_type(8)));

// W fragment-linear, per 16-col n-frag:
//   byte = (n*7 + kk)*1024 + col16*64 + ks*16 + e*2   (zero-padded k>=196)
__device__ unsigned short g_Wb4[49 * 7 * 16 * 32];          // 351 KB
// x patchified, bf16, row stride 224 ushorts (zero-padded k = 196..223)
__device__ unsigned short g_xb[(size_t)ROWS_TOTAL * XST];   // 58.7 MB

__device__ __forceinline__ unsigned short f2bf(float f) {
    unsigned int u = __builtin_bit_cast(unsigned int, f);
    u += 0x7fffu + ((u >> 16) & 1u);        // round-to-nearest-even
    return (unsigned short)(u >> 16);
}

__global__ void prep_w(const float* __restrict__ W) {
    int t = blockIdx.x * 256 + threadIdx.x;   // 784 cols * 56 k-quads
    if (t >= 784 * 56) return;
    int col = t / 56;
    int k0  = (t - col * 56) * 4;
    uint2 pk;
    if (k0 < 196) {
        f32x4 d = *(const f32x4*)(W + col * 196 + k0);
        pk.x = (unsigned int)f2bf(d[0]) | ((unsigned int)f2bf(d[1]) << 16);
        pk.y = (unsigned int)f2bf(d[2]) | ((unsigned int)f2bf(d[3]) << 16);
    } else {
        pk.x = 0u; pk.y = 0u;
    }
    int ng = col >> 4, col16 = col & 15;
    int kk = k0 >> 5, rem = k0 & 31, ks = rem >> 3, e0 = rem & 7;
    size_t di = (size_t)((ng * 7 + kk) * 16 + col16) * 32 + ks * 8 + e0;
    *(uint2*)(g_Wb4 + di) = pk;
}

// patchify: x[32768,28,28] fp32 -> g_xb[131072][224] bf16 (zero-padded)
__global__ void prep_x(const float* __restrict__ x) {
    const int NV = ROWS_TOTAL / 4 * 784 / 4;            // 6,422,528 float4s
    const f32x4* xv = (const f32x4*)x;
    for (int v = blockIdx.x * 256 + threadIdx.x; v < NV; v += gridDim.x * 256) {
        f32x4 d = xv[v];
        int F   = v * 4;
        int img = F / 784;
        int rem = F - img * 784;
        int h   = rem / 28;
        int w0  = rem - h * 28;          // in {0,4,...,24}
        int ph  = h / 14;
        int r   = h - ph * 14;
        int rowb = img * 4 + ph * 2;
        #pragma unroll
        for (int p = 0; p < 2; ++p) {
            int w  = w0 + 2 * p;         // even => bf16 pair stays inside one patch
            int pw = (w >= 14) ? 1 : 0;
            int c  = w - pw * 14;
            int row = rowb + pw;
            unsigned int pack = (unsigned int)f2bf(d[2 * p]) |
                                ((unsigned int)f2bf(d[2 * p + 1]) << 16);
            *(unsigned int*)((char*)g_xb + (size_t)row * (XST * 2) + (r * 14 + c) * 2) = pack;
        }
    }
    // zero pad k = 196..223 for every row
    for (int t = blockIdx.x * 256 + threadIdx.x; t < ROWS_TOTAL * 7; t += gridDim.x * 256) {
        int row = t / 7;
        int j   = t - row * 7;
        *(uint2*)((char*)g_xb + (size_t)row * (XST * 2) + 392 + j * 8) = (uint2){0u, 0u};
    }
}

#define LDX(XF, RT) do {                                                        \
    const char* xp_ = (const char*)g_xb + ((size_t)(RT) * 16 + lrow) * 448 + lk * 16; \
    _Pragma("unroll") for (int kk = 0; kk < 7; ++kk)                            \
        XF[kk] = *(const s16x8*)(xp_ + kk * 64);                                \
} while (0)

#define CS4(XF, RT) do {                                                        \
    f32x4 acc[4];                                                               \
    _Pragma("unroll") for (int n = 0; n < 4; ++n) acc[n] = bias[n];             \
    _Pragma("unroll") for (int kk = 0; kk < 7; ++kk)                            \
        _Pragma("unroll") for (int n = 0; n < 4; ++n)                           \
            acc[n] = __builtin_amdgcn_mfma_f32_16x16x32_bf16(                   \
                wf[n][kk], XF[kk], acc[n], 0, 0, 0);                            \
    float* orow_ = out + ((size_t)(RT) * 16 + lrow) * 784 + n0 * 16 + lk * 4;   \
    _Pragma("unroll") for (int n = 0; n < 4; ++n)                               \
        *(f32x4*)(orow_ + n * 16) = acc[n];                                     \
} while (0)

#define CS1(XF, RT) do {                                                        \
    f32x4 acc0 = bias0;                                                         \
    _Pragma("unroll") for (int kk = 0; kk < 7; ++kk)                            \
        acc0 = __builtin_amdgcn_mfma_f32_16x16x32_bf16(                         \
            wf1[kk], XF[kk], acc0, 0, 0, 0);                                    \
    float* orow_ = out + ((size_t)(RT) * 16 + lrow) * 784 + 768 + lk * 4;       \
    *(f32x4*)orow_ = acc0;                                                      \
} while (0)

// Pure streaming GEMM: no LDS, no barriers. Wave owns 64 output cols
// (4 n-frags; W held in 112 VGPR, pinned by waves_per_eu(2,2)) and loops
// over 16-row tiles with double-buffered xf prefetch.
// bid = (s&7) + 8*((s>>3) + 5*cg): all 13 cg-siblings of slice s share
// bid%8 -> same XCD -> x tiles L2-hit x13, out lines complete in one L2.
__global__ __launch_bounds__(256)
__attribute__((amdgpu_waves_per_eu(2, 2)))
void patch_linear_mfma(const float* __restrict__ blin,
                       float* __restrict__ out) {
    const int tid  = threadIdx.x;
    const int l    = tid & 63;
    const int wv   = tid >> 6;          // 0..3
    const int lrow = l & 15;
    const int lk   = l >> 4;

    const int bid = blockIdx.x;         // 0..519
    const int r   = bid & 7;
    const int t   = bid >> 3;           // 0..64
    const int cg  = t / 5;              // 0..12
    const int q   = t - cg * 5;         // 0..4
    const int s   = q * 8 + r;          // slice 0..39

    const int slot = s * 4 + wv;        // 0..159
    const int NT   = ROWS_TOTAL / 16;   // 8192

    if (cg < 12) {
        const int n0 = cg * 4;
        // ---- W fragments -> registers, once ----
        s16x8 wf[4][7];
        #pragma unroll
        for (int n = 0; n < 4; ++n) {
            const char* wp = (const char*)g_Wb4 +
                             (size_t)((n0 + n) * 7) * 1024 + lrow * 64 + lk * 16;
            #pragma unroll
            for (int kk = 0; kk < 7; ++kk)
                wf[n][kk] = *(const s16x8*)(wp + kk * 1024);
        }
        f32x4 bias[4];
        #pragma unroll
        for (int n = 0; n < 4; ++n)
            bias[n] = *(const f32x4*)(blin + (n0 + n) * 16 + lk * 4);

        int rt = slot;
        s16x8 xa[7], xb_[7];
        LDX(xa, rt);
        for (;;) {
            int rtn = rt + 160;
            if (rtn < NT) {
                LDX(xb_, rtn);
                CS4(xa, rt);
                rt = rtn;
            } else {
                CS4(xa, rt);
                break;
            }
            rtn = rt + 160;
            if (rtn < NT) {
                LDX(xa, rtn);
                CS4(xb_, rt);
                rt = rtn;
            } else {
                CS4(xb_, rt);
                break;
            }
        }
    } else {
        // tail cols 768..783 (single n-frag)
        s16x8 wf1[7];
        const char* wp = (const char*)g_Wb4 + (size_t)(48 * 7) * 1024 + lrow * 64 + lk * 16;
        #pragma unroll
        for (int kk = 0; kk < 7; ++kk)
            wf1[kk] = *(const s16x8*)(wp + kk * 1024);
        const f32x4 bias0 = *(const f32x4*)(blin + 768 + lk * 4);

        int rt = slot;
        s16x8 xa[7], xb_[7];
        LDX(xa, rt);
        for (;;) {
            int rtn = rt + 160;
            if (rtn < NT) {
                LDX(xb_, rtn);
                CS1(xa, rt);
                rt = rtn;
            } else {
                CS1(xa, rt);
                break;
            }
            rtn = rt + 160;
            if (rtn < NT) {
                LDX(xa, rtn);
                CS1(xb_, rt);
                rt = rtn;
            } else {
                CS1(xb_, rt);
                break;
            }
        }
    }
}

extern "C" void kernel_launch(void* const* d_in, const int* in_sizes, int n_in,
                              void* d_out, int out_size, void* d_ws, size_t ws_size,
                              hipStream_t stream) {
    const float* x    = (const float*)d_in[0];   // [32768,1,28,28]
    const float* Wlin = (const float*)d_in[1];   // [784,196]
    const float* blin = (const float*)d_in[2];   // [784]
    float* out = (float*)d_out;                  // [32768,4,784]

    prep_w<<<(784 * 56 + 255) / 256, 256, 0, stream>>>(Wlin);
    prep_x<<<4096, 256, 0, stream>>>(x);

    dim3 grid(520);                              // 13 cg * 40 slices, XCD-grouped
    dim3 block(256);
    patch_linear_mfma<<<grid, block, 0, stream>>>(blin, out);
}

// Round 17
// 192.658 us; speedup vs baseline: 1.3738x; 1.1584x over previous
//
#include <hip/hip_runtime.h>

#define ROWS_TOTAL 131072
#define XST 224             // g_xb row stride in bf16 elements (448 B, zero-padded)

typedef float f32x4 __attribute__((ext_vector_type(4)));
typedef short s16x8 __attribute__((ext_vector_type(8)));

// W fragment-linear, per 16-col n-frag:
//   byte = (n*7 + kk)*1024 + col16*64 + ks*16 + e*2   (zero-padded k>=196)
__device__ unsigned short g_Wb4[49 * 7 * 16 * 32];          // 351 KB
// x patchified, bf16, row stride 224 ushorts (zero-padded k = 196..223)
__device__ unsigned short g_xb[(size_t)ROWS_TOTAL * XST];   // 58.7 MB

__device__ __forceinline__ unsigned short f2bf(float f) {
    unsigned int u = __builtin_bit_cast(unsigned int, f);
    u += 0x7fffu + ((u >> 16) & 1u);        // round-to-nearest-even
    return (unsigned short)(u >> 16);
}

__global__ void prep_w(const float* __restrict__ W) {
    int t = blockIdx.x * 256 + threadIdx.x;   // 784 cols * 56 k-quads
    if (t >= 784 * 56) return;
    int col = t / 56;
    int k0  = (t - col * 56) * 4;
    uint2 pk;
    if (k0 < 196) {
        f32x4 d = *(const f32x4*)(W + col * 196 + k0);
        pk.x = (unsigned int)f2bf(d[0]) | ((unsigned int)f2bf(d[1]) << 16);
        pk.y = (unsigned int)f2bf(d[2]) | ((unsigned int)f2bf(d[3]) << 16);
    } else {
        pk.x = 0u; pk.y = 0u;
    }
    int ng = col >> 4, col16 = col & 15;
    int kk = k0 >> 5, rem = k0 & 31, ks = rem >> 3, e0 = rem & 7;
    size_t di = (size_t)((ng * 7 + kk) * 16 + col16) * 32 + ks * 8 + e0;
    *(uint2*)(g_Wb4 + di) = pk;
}

// patchify: x[32768,28,28] fp32 -> g_xb[131072][224] bf16 (zero-padded)
__global__ void prep_x(const float* __restrict__ x) {
    const int NV = ROWS_TOTAL / 4 * 784 / 4;            // 6,422,528 float4s
    const f32x4* xv = (const f32x4*)x;
    for (int v = blockIdx.x * 256 + threadIdx.x; v < NV; v += gridDim.x * 256) {
        f32x4 d = xv[v];
        int F   = v * 4;
        int img = F / 784;
        int rem = F - img * 784;
        int h   = rem / 28;
        int w0  = rem - h * 28;          // in {0,4,...,24}
        int ph  = h / 14;
        int r   = h - ph * 14;
        int rowb = img * 4 + ph * 2;
        #pragma unroll
        for (int p = 0; p < 2; ++p) {
            int w  = w0 + 2 * p;         // even => bf16 pair stays inside one patch
            int pw = (w >= 14) ? 1 : 0;
            int c  = w - pw * 14;
            int row = rowb + pw;
            unsigned int pack = (unsigned int)f2bf(d[2 * p]) |
                                ((unsigned int)f2bf(d[2 * p + 1]) << 16);
            *(unsigned int*)((char*)g_xb + (size_t)row * (XST * 2) + (r * 14 + c) * 2) = pack;
        }
    }
    // zero pad k = 196..223 for every row
    for (int t = blockIdx.x * 256 + threadIdx.x; t < ROWS_TOTAL * 7; t += gridDim.x * 256) {
        int row = t / 7;
        int j   = t - row * 7;
        *(uint2*)((char*)g_xb + (size_t)row * (XST * 2) + 392 + j * 8) = (uint2){0u, 0u};
    }
}

__device__ __forceinline__ void gload_lds16(void* lds, const void* g) {
    __builtin_amdgcn_global_load_lds(
        (const __attribute__((address_space(1))) unsigned int*)g,
        (__attribute__((address_space(3))) unsigned int*)lds, 16, 0, 0);
}

// R11 anatomy, 64-col tiles: block = 128 rows x 64 cols (tail block: 16 cols).
// sW 28 KiB via linear DMA -> 4 resident blocks/CU (16 waves). One barrier.
// Each output row strip = 256 B = 2 FULL 128-B lines (no split lines).
// rg-major order (bid = cg + 13*rg): the 13 col-siblings of a row-group are
// launch-adjacent -> x tile L2/L3-hot, row-boundary lines close quickly.
__global__ __launch_bounds__(256, 4)
void patch_linear_mfma(const float* __restrict__ blin,
                       float* __restrict__ out) {
    __shared__ __align__(16) char sW[28 * 1024];   // [nfrag][kk][1 KiB]

    const int tid  = threadIdx.x;
    const int l    = tid & 63;
    const int wv   = tid >> 6;          // 0..3
    const int lrow = l & 15;
    const int lk   = l >> 4;

    const int bid = blockIdx.x;
    const int rg  = bid / 13;           // row group (128 rows), 0..1023
    const int cg  = bid - rg * 13;      // col group: 0..11 = 64 cols, 12 = 16 cols

    // ---- stage W group: nch x 1 KiB linear async DMA ----
    const int nch = (cg < 12) ? 28 : 7;
    const char* wsrc = (const char*)g_Wb4 + (size_t)cg * 28672 + l * 16;
    #pragma unroll
    for (int c = 0; c < 7; ++c) {
        int ch = wv + c * 4;
        if (ch < nch) gload_lds16(sW + ch * 1024, wsrc + ch * 1024);
    }

    // ---- x fragments -> registers (fly under the DMA) ----
    const char* xb = (const char*)g_xb +
                     ((size_t)rg * 128 + wv * 32 + lrow) * 448 + lk * 16;
    s16x8 xf[2][7];
    #pragma unroll
    for (int m = 0; m < 2; ++m)
        #pragma unroll
        for (int kk = 0; kk < 7; ++kk)
            xf[m][kk] = *(const s16x8*)(xb + m * (16 * 448) + kk * 64);

    __syncthreads();   // drains DMA + xf loads; the only barrier

    const char* wb = sW + lrow * 64 + lk * 16;
    float* orow = out + ((size_t)rg * 128 + wv * 32 + lrow) * 784 + cg * 64 + lk * 4;

    if (cg < 12) {
        f32x4 acc[2][4];
        #pragma unroll
        for (int n = 0; n < 4; ++n) {
            f32x4 b = *(const f32x4*)(blin + cg * 64 + n * 16 + lk * 4);
            acc[0][n] = b;
            acc[1][n] = b;
        }
        #pragma unroll
        for (int kk = 0; kk < 7; ++kk)
            #pragma unroll
            for (int n = 0; n < 4; ++n) {
                s16x8 wf = *(const s16x8*)(wb + (n * 7 + kk) * 1024);
                acc[0][n] = __builtin_amdgcn_mfma_f32_16x16x32_bf16(wf, xf[0][kk], acc[0][n], 0, 0, 0);
                acc[1][n] = __builtin_amdgcn_mfma_f32_16x16x32_bf16(wf, xf[1][kk], acc[1][n], 0, 0, 0);
            }
        // store: 8 dwordx4/lane; block covers 2 full 128-B lines per row
        #pragma unroll
        for (int m = 0; m < 2; ++m)
            #pragma unroll
            for (int n = 0; n < 4; ++n)
                *(f32x4*)(orow + m * (16 * 784) + n * 16) = acc[m][n];
    } else {
        // tail: cols 768..783 (one n-frag)
        f32x4 b = *(const f32x4*)(blin + 768 + lk * 4);
        f32x4 acc0 = b, acc1 = b;
        #pragma unroll
        for (int kk = 0; kk < 7; ++kk) {
            s16x8 wf = *(const s16x8*)(wb + kk * 1024);
            acc0 = __builtin_amdgcn_mfma_f32_16x16x32_bf16(wf, xf[0][kk], acc0, 0, 0, 0);
            acc1 = __builtin_amdgcn_mfma_f32_16x16x32_bf16(wf, xf[1][kk], acc1, 0, 0, 0);
        }
        *(f32x4*)(orow) = acc0;
        *(f32x4*)(orow + 16 * 784) = acc1;
    }
}

extern "C" void kernel_launch(void* const* d_in, const int* in_sizes, int n_in,
                              void* d_out, int out_size, void* d_ws, size_t ws_size,
                              hipStream_t stream) {
    const float* x    = (const float*)d_in[0];   // [32768,1,28,28]
    const float* Wlin = (const float*)d_in[1];   // [784,196]
    const float* blin = (const float*)d_in[2];   // [784]
    float* out = (float*)d_out;                  // [32768,4,784]

    prep_w<<<(784 * 56 + 255) / 256, 256, 0, stream>>>(Wlin);
    prep_x<<<4096, 256, 0, stream>>>(x);

    dim3 grid(1024 * 13);                        // bid = cg + 13*rg (rg-major)
    dim3 block(256);
    patch_linear_mfma<<<grid, block, 0, stream>>>(blin, out);
}

// Round 18
// 154.473 us; speedup vs baseline: 1.7134x; 1.2472x over previous
//
#include <hip/hip_runtime.h>

#define ROWS_TOTAL 131072
#define XST 224             // g_xb row stride in bf16 elements (448 B, zero-padded)

typedef float f32x4 __attribute__((ext_vector_type(4)));
typedef short s16x8 __attribute__((ext_vector_type(8)));

// W fragment-linear, per 16-col n-frag:
//   byte = (n*7 + kk)*1024 + col16*64 + ks*16 + e*2   (zero-padded k>=196)
__device__ unsigned short g_Wb4[49 * 7 * 16 * 32];          // 351 KB
// x patchified, bf16, row stride 224 ushorts (zero-padded k = 196..223)
__device__ unsigned short g_xb[(size_t)ROWS_TOTAL * XST];   // 58.7 MB

__device__ __forceinline__ unsigned short f2bf(float f) {
    unsigned int u = __builtin_bit_cast(unsigned int, f);
    u += 0x7fffu + ((u >> 16) & 1u);        // round-to-nearest-even
    return (unsigned short)(u >> 16);
}

__global__ void prep_w(const float* __restrict__ W) {
    int t = blockIdx.x * 256 + threadIdx.x;   // 784 cols * 56 k-quads
    if (t >= 784 * 56) return;
    int col = t / 56;
    int k0  = (t - col * 56) * 4;
    uint2 pk;
    if (k0 < 196) {
        f32x4 d = *(const f32x4*)(W + col * 196 + k0);
        pk.x = (unsigned int)f2bf(d[0]) | ((unsigned int)f2bf(d[1]) << 16);
        pk.y = (unsigned int)f2bf(d[2]) | ((unsigned int)f2bf(d[3]) << 16);
    } else {
        pk.x = 0u; pk.y = 0u;
    }
    int ng = col >> 4, col16 = col & 15;
    int kk = k0 >> 5, rem = k0 & 31, ks = rem >> 3, e0 = rem & 7;
    size_t di = (size_t)((ng * 7 + kk) * 16 + col16) * 32 + ks * 8 + e0;
    *(uint2*)(g_Wb4 + di) = pk;
}

// patchify: x[32768,28,28] fp32 -> g_xb[131072][224] bf16 (zero-padded)
__global__ void prep_x(const float* __restrict__ x) {
    const int NV = ROWS_TOTAL / 4 * 784 / 4;            // 6,422,528 float4s
    const f32x4* xv = (const f32x4*)x;
    for (int v = blockIdx.x * 256 + threadIdx.x; v < NV; v += gridDim.x * 256) {
        f32x4 d = xv[v];
        int F   = v * 4;
        int img = F / 784;
        int rem = F - img * 784;
        int h   = rem / 28;
        int w0  = rem - h * 28;          // in {0,4,...,24}
        int ph  = h / 14;
        int r   = h - ph * 14;
        int rowb = img * 4 + ph * 2;
        #pragma unroll
        for (int p = 0; p < 2; ++p) {
            int w  = w0 + 2 * p;         // even => bf16 pair stays inside one patch
            int pw = (w >= 14) ? 1 : 0;
            int c  = w - pw * 14;
            int row = rowb + pw;
            unsigned int pack = (unsigned int)f2bf(d[2 * p]) |
                                ((unsigned int)f2bf(d[2 * p + 1]) << 16);
            *(unsigned int*)((char*)g_xb + (size_t)row * (XST * 2) + (r * 14 + c) * 2) = pack;
        }
    }
    // zero pad k = 196..223 for every row
    for (int t = blockIdx.x * 256 + threadIdx.x; t < ROWS_TOTAL * 7; t += gridDim.x * 256) {
        int row = t / 7;
        int j   = t - row * 7;
        *(uint2*)((char*)g_xb + (size_t)row * (XST * 2) + 392 + j * 8) = (uint2){0u, 0u};
    }
}

__device__ __forceinline__ void gload_lds16(void* lds, const void* g) {
    __builtin_amdgcn_global_load_lds(
        (const __attribute__((address_space(1))) unsigned int*)g,
        (__attribute__((address_space(3))) unsigned int*)lds, 16, 0, 0);
}

// Block: 256 out rows x 112 out cols; 8 waves, wave = 32 rows (m0 then m1).
// W group (49 KiB) staged once per block via linear DMA -> 2 blocks/CU
// (16 waves). ONE barrier. xf1 loads fly under m0's MFMAs; m0 stores issue
// before the m1 phase. All output stores NONTEMPORAL (write-once data; keeps
// W/x hot in L2). Same-XCD sibling swizzle: bid = xcd + 8*(q*7+cg),
// rg = q*8+xcd -> 7 cg-siblings of a row-group co-run on one XCD.
__global__ __launch_bounds__(512, 4)
void patch_linear_mfma(const float* __restrict__ blin,
                       float* __restrict__ out) {
    __shared__ __align__(16) char sW[49 * 1024];   // [nn][kk][1 KiB]

    const int tid  = threadIdx.x;
    const int l    = tid & 63;
    const int wv   = tid >> 6;          // 0..7
    const int lrow = l & 15;
    const int lk   = l >> 4;

    const int bid = blockIdx.x;         // 0..3583
    const int xcd = bid & 7;
    const int t   = bid >> 3;           // 0..447
    const int q   = t / 7;              // 0..63
    const int cg  = t - q * 7;          // 0..6
    const int rg  = q * 8 + xcd;        // 0..511 (256-row group)

    // ---- stage W group: 49 x 1 KiB linear async DMA (7 or 6 chunks/wave) ----
    const char* wsrc = (const char*)g_Wb4 + (size_t)cg * 50176 + l * 16;
    #pragma unroll
    for (int c = 0; c < 7; ++c) {
        int ch = wv + c * 8;
        if (ch < 49) gload_lds16(sW + ch * 1024, wsrc + ch * 1024);
    }

    // ---- xf (m=0 half) -> registers; flies under the DMA ----
    const size_t row0 = (size_t)rg * 256 + wv * 32 + lrow;
    const char* xb = (const char*)g_xb + row0 * 448 + lk * 16;
    s16x8 xf0[7];
    #pragma unroll
    for (int kk = 0; kk < 7; ++kk)
        xf0[kk] = *(const s16x8*)(xb + kk * 64);

    // ---- acc init = bias (both halves) ----
    f32x4 acc0[7], acc1[7];
    #pragma unroll
    for (int n = 0; n < 7; ++n) {
        f32x4 b = *(const f32x4*)(blin + cg * 112 + n * 16 + lk * 4);
        acc0[n] = b;
        acc1[n] = b;
    }

    __syncthreads();   // drains DMA; the only barrier

    // issue m=1 xf loads immediately: they fly under the m0 MFMA phase
    s16x8 xf1[7];
    #pragma unroll
    for (int kk = 0; kk < 7; ++kk)
        xf1[kk] = *(const s16x8*)(xb + 16 * 448 + kk * 64);

    const char* wb = sW + lrow * 64 + lk * 16;

    // ---- m0: 49 ds_read + 49 MFMA ----
    #pragma unroll
    for (int kk = 0; kk < 7; ++kk)
        #pragma unroll
        for (int n = 0; n < 7; ++n) {
            s16x8 wf = *(const s16x8*)(wb + (n * 7 + kk) * 1024);
            acc0[n] = __builtin_amdgcn_mfma_f32_16x16x32_bf16(wf, xf0[kk], acc0[n], 0, 0, 0);
        }

    // m0 stores (nontemporal): 7 dwordx4/lane, full 64-B sectors
    float* orow0 = out + row0 * 784 + cg * 112 + lk * 4;
    #pragma unroll
    for (int n = 0; n < 7; ++n)
        __builtin_nontemporal_store(acc0[n], (f32x4*)(orow0 + n * 16));

    // ---- m1: 49 ds_read + 49 MFMA ----
    #pragma unroll
    for (int kk = 0; kk < 7; ++kk)
        #pragma unroll
        for (int n = 0; n < 7; ++n) {
            s16x8 wf = *(const s16x8*)(wb + (n * 7 + kk) * 1024);
            acc1[n] = __builtin_amdgcn_mfma_f32_16x16x32_bf16(wf, xf1[kk], acc1[n], 0, 0, 0);
        }

    float* orow1 = orow0 + 16 * 784;
    #pragma unroll
    for (int n = 0; n < 7; ++n)
        __builtin_nontemporal_store(acc1[n], (f32x4*)(orow1 + n * 16));
}

extern "C" void kernel_launch(void* const* d_in, const int* in_sizes, int n_in,
                              void* d_out, int out_size, void* d_ws, size_t ws_size,
                              hipStream_t stream) {
    const float* x    = (const float*)d_in[0];   // [32768,1,28,28]
    const float* Wlin = (const float*)d_in[1];   // [784,196]
    const float* blin = (const float*)d_in[2];   // [784]
    float* out = (float*)d_out;                  // [32768,4,784]

    prep_w<<<(784 * 56 + 255) / 256, 256, 0, stream>>>(Wlin);
    prep_x<<<4096, 256, 0, stream>>>(x);

    dim3 grid(512 * 7);                          // 3584 blocks, same-XCD siblings
    dim3 block(512);
    patch_linear_mfma<<<grid, block, 0, stream>>>(blin, out);
}